// Round 3
// baseline (198.124 us; speedup 1.0000x reference)
//
#include <hip/hip_runtime.h>

typedef short short8 __attribute__((ext_vector_type(8)));
typedef float f32x4 __attribute__((ext_vector_type(4)));

#define AS1 __attribute__((address_space(1)))
#define AS3 __attribute__((address_space(3)))

__device__ __forceinline__ void gload16(const void* g, void* l) {
    __builtin_amdgcn_global_load_lds((const AS1 unsigned int*)g, (AS3 unsigned int*)l, 16, 0, 0);
}

__device__ __forceinline__ unsigned short f2bf(float f) {
    union { float f; unsigned u; } c; c.f = f;
    unsigned r = (c.u + 0x7FFFu + ((c.u >> 16) & 1u)) >> 16;
    return (unsigned short)r;
}

__device__ __forceinline__ unsigned cvtpk(float a, float b) {
    unsigned r;
    asm("v_cvt_pk_bf16_f32 %0, %1, %2" : "=v"(r) : "v"(a), "v"(b));
    return r;
}

__device__ __forceinline__ void mfma16(f32x4& d, short8 a, short8 b) {
    asm("v_mfma_f32_16x16x32_bf16 %0, %1, %2, %0" : "+v"(d) : "v"(a), "v"(b));
}

// q pre-scale: 1/sqrt(64) * log2(e)  -> softmax via exp2
#define QSCALE 0.18033688011112042f

// ---------------- fp32 -> bf16 convert ----------------
__global__ __launch_bounds__(256) void cvt_f32_bf16(const float* __restrict__ in,
                                                    unsigned short* __restrict__ out, int n4) {
    int idx = blockIdx.x * 256 + threadIdx.x;
    int stride = gridDim.x * 256;
    for (int i = idx; i < n4; i += stride) {
        float4 v = ((const float4*)in)[i];
        ushort4 o;
        o.x = f2bf(v.x); o.y = f2bf(v.y); o.z = f2bf(v.z); o.w = f2bf(v.w);
        ((ushort4*)out)[i] = o;
    }
}

// ---------------- 256x256 8-phase NT GEMM: C = A[M,K] * B[N,K]^T + bias ----------------
// 512 threads = 8 waves (2 M x 4 N). BK=64 split in 2 kslices of 32.
// LDS (dynamic 128KB): As[2buf][2ks][256][32], Bs same. XOR-swizzle c16 ^= (row>>1)&3.
// Counted-vmcnt pipeline: stage A0,B0(t+1) @ph0; A1,B1(t+1) @ph1.
//   ph1: vmcnt(8) completes A1,B1(t) (read ph2/3). ph3: vmcnt(4) completes A0,B0(t+1).
template <int EPI>
__global__ __launch_bounds__(512, 2) void gemm256(
    const unsigned short* __restrict__ A, const unsigned short* __restrict__ B,
    const float* __restrict__ bias, int K, int NTN, int N,
    float* __restrict__ Cf, unsigned short* __restrict__ qb,
    unsigned short* __restrict__ kb, unsigned short* __restrict__ vtb) {
    extern __shared__ unsigned short lds[];
    unsigned short* As = lds;            // + buf*16384 + ks*8192 + row*32 + c16*8
    unsigned short* Bs = lds + 32768;

    const int tid = threadIdx.x;
    const int lane = tid & 63;
    const int wid = tid >> 6;
    const int lr = lane & 15, lg = lane >> 4;
    const int xsw = (lr >> 1) & 3;       // read-side swizzle
    const int wm = (wid >> 2) * 128;
    const int wn = (wid & 3) * 64;

    const int cpx = gridDim.x >> 3;      // grid % 8 == 0 (384 / 128)
    const int wg = blockIdx.x;
    const int sw = (wg & 7) * cpx + (wg >> 3);
    const int m0 = (sw / NTN) * 256;
    const int n0 = (sw % NTN) * 256;

    // staging: thread -> physical slot (row = r*128 + tid>>2, c16 = tid&3),
    // global source col pre-swizzled so read-side XOR recovers linear data.
    const int srow = tid >> 2;
    const int sc16 = ((tid & 3) ^ ((tid >> 3) & 3)) * 8;
    const unsigned short* Ag = A + (size_t)(m0 + srow) * K + sc16;
    const unsigned short* Bg = B + (size_t)(n0 + srow) * K + sc16;
    unsigned short* AsW = As + tid * 8;
    unsigned short* BsW = Bs + tid * 8;
    const size_t rK = (size_t)128 * K;

    f32x4 acc[8][4];
#pragma unroll
    for (int i = 0; i < 8; i++)
#pragma unroll
        for (int j = 0; j < 4; j++) acc[i][j] = (f32x4){0.f, 0.f, 0.f, 0.f};

    const int NT = K >> 6;

    // prologue: tile 0 -> buf0 (A0,B0 first, then A1,B1)
    gload16(Ag, AsW);
    gload16(Ag + rK, AsW + 4096);
    gload16(Bg, BsW);
    gload16(Bg + rK, BsW + 4096);
    gload16(Ag + 32, AsW + 8192);
    gload16(Ag + rK + 32, AsW + 8192 + 4096);
    gload16(Bg + 32, BsW + 8192);
    gload16(Bg + rK + 32, BsW + 8192 + 4096);
    asm volatile("s_waitcnt vmcnt(4)" ::: "memory");  // A0,B0(0) done
    __builtin_amdgcn_s_barrier();

    for (int t = 0; t < NT; ++t) {
        const int buf = (t & 1) << 14;
        const int nbf = buf ^ 16384;
        const bool last = (t == NT - 1);
        const size_t kn = (size_t)(t + 1) * 64;
        const unsigned short* Ab0 = As + buf + (size_t)(wm + lr) * 32;
        const unsigned short* Bb0 = Bs + buf + (size_t)(wn + lr) * 32;
        const int co = (lg ^ xsw) * 8;
        short8 a0, a1, a2, a3, b0, b1, b2, b3;

        // ---------- phase 0: ks0, M-frags 0-3 ----------
        if (!last) {
            gload16(Ag + kn, AsW + nbf);
            gload16(Ag + rK + kn, AsW + nbf + 4096);
            gload16(Bg + kn, BsW + nbf);
            gload16(Bg + rK + kn, BsW + nbf + 4096);
        }
        b0 = *(const short8*)(Bb0 + co);
        b1 = *(const short8*)(Bb0 + 512 + co);
        b2 = *(const short8*)(Bb0 + 1024 + co);
        b3 = *(const short8*)(Bb0 + 1536 + co);
        a0 = *(const short8*)(Ab0 + co);
        a1 = *(const short8*)(Ab0 + 512 + co);
        a2 = *(const short8*)(Ab0 + 1024 + co);
        a3 = *(const short8*)(Ab0 + 1536 + co);
        __builtin_amdgcn_s_barrier();
        asm volatile("s_waitcnt lgkmcnt(0)" ::: "memory");
        __builtin_amdgcn_sched_barrier(0);
        __builtin_amdgcn_s_setprio(1);
        mfma16(acc[0][0], a0, b0); mfma16(acc[0][1], a0, b1);
        mfma16(acc[0][2], a0, b2); mfma16(acc[0][3], a0, b3);
        mfma16(acc[1][0], a1, b0); mfma16(acc[1][1], a1, b1);
        mfma16(acc[1][2], a1, b2); mfma16(acc[1][3], a1, b3);
        mfma16(acc[2][0], a2, b0); mfma16(acc[2][1], a2, b1);
        mfma16(acc[2][2], a2, b2); mfma16(acc[2][3], a2, b3);
        mfma16(acc[3][0], a3, b0); mfma16(acc[3][1], a3, b1);
        mfma16(acc[3][2], a3, b2); mfma16(acc[3][3], a3, b3);
        __builtin_amdgcn_s_setprio(0);
        __builtin_amdgcn_s_barrier();

        // ---------- phase 1: ks0, M-frags 4-7 ----------
        if (!last) {
            gload16(Ag + kn + 32, AsW + nbf + 8192);
            gload16(Ag + rK + kn + 32, AsW + nbf + 8192 + 4096);
            gload16(Bg + kn + 32, BsW + nbf + 8192);
            gload16(Bg + rK + kn + 32, BsW + nbf + 8192 + 4096);
        }
        a0 = *(const short8*)(Ab0 + 2048 + co);
        a1 = *(const short8*)(Ab0 + 2560 + co);
        a2 = *(const short8*)(Ab0 + 3072 + co);
        a3 = *(const short8*)(Ab0 + 3584 + co);
        if (last) asm volatile("s_waitcnt vmcnt(0)" ::: "memory");
        else      asm volatile("s_waitcnt vmcnt(8)" ::: "memory");
        __builtin_amdgcn_s_barrier();
        asm volatile("s_waitcnt lgkmcnt(0)" ::: "memory");
        __builtin_amdgcn_sched_barrier(0);
        __builtin_amdgcn_s_setprio(1);
        mfma16(acc[4][0], a0, b0); mfma16(acc[4][1], a0, b1);
        mfma16(acc[4][2], a0, b2); mfma16(acc[4][3], a0, b3);
        mfma16(acc[5][0], a1, b0); mfma16(acc[5][1], a1, b1);
        mfma16(acc[5][2], a1, b2); mfma16(acc[5][3], a1, b3);
        mfma16(acc[6][0], a2, b0); mfma16(acc[6][1], a2, b1);
        mfma16(acc[6][2], a2, b2); mfma16(acc[6][3], a2, b3);
        mfma16(acc[7][0], a3, b0); mfma16(acc[7][1], a3, b1);
        mfma16(acc[7][2], a3, b2); mfma16(acc[7][3], a3, b3);
        __builtin_amdgcn_s_setprio(0);
        __builtin_amdgcn_s_barrier();

        // ---------- phase 2: ks1, M-frags 0-3 ----------
        b0 = *(const short8*)(Bb0 + 8192 + co);
        b1 = *(const short8*)(Bb0 + 8192 + 512 + co);
        b2 = *(const short8*)(Bb0 + 8192 + 1024 + co);
        b3 = *(const short8*)(Bb0 + 8192 + 1536 + co);
        a0 = *(const short8*)(Ab0 + 8192 + co);
        a1 = *(const short8*)(Ab0 + 8192 + 512 + co);
        a2 = *(const short8*)(Ab0 + 8192 + 1024 + co);
        a3 = *(const short8*)(Ab0 + 8192 + 1536 + co);
        __builtin_amdgcn_s_barrier();
        asm volatile("s_waitcnt lgkmcnt(0)" ::: "memory");
        __builtin_amdgcn_sched_barrier(0);
        __builtin_amdgcn_s_setprio(1);
        mfma16(acc[0][0], a0, b0); mfma16(acc[0][1], a0, b1);
        mfma16(acc[0][2], a0, b2); mfma16(acc[0][3], a0, b3);
        mfma16(acc[1][0], a1, b0); mfma16(acc[1][1], a1, b1);
        mfma16(acc[1][2], a1, b2); mfma16(acc[1][3], a1, b3);
        mfma16(acc[2][0], a2, b0); mfma16(acc[2][1], a2, b1);
        mfma16(acc[2][2], a2, b2); mfma16(acc[2][3], a2, b3);
        mfma16(acc[3][0], a3, b0); mfma16(acc[3][1], a3, b1);
        mfma16(acc[3][2], a3, b2); mfma16(acc[3][3], a3, b3);
        __builtin_amdgcn_s_setprio(0);
        __builtin_amdgcn_s_barrier();

        // ---------- phase 3: ks1, M-frags 4-7 ----------
        a0 = *(const short8*)(Ab0 + 8192 + 2048 + co);
        a1 = *(const short8*)(Ab0 + 8192 + 2560 + co);
        a2 = *(const short8*)(Ab0 + 8192 + 3072 + co);
        a3 = *(const short8*)(Ab0 + 8192 + 3584 + co);
        asm volatile("s_waitcnt vmcnt(4)" ::: "memory");
        __builtin_amdgcn_s_barrier();
        asm volatile("s_waitcnt lgkmcnt(0)" ::: "memory");
        __builtin_amdgcn_sched_barrier(0);
        __builtin_amdgcn_s_setprio(1);
        mfma16(acc[4][0], a0, b0); mfma16(acc[4][1], a0, b1);
        mfma16(acc[4][2], a0, b2); mfma16(acc[4][3], a0, b3);
        mfma16(acc[5][0], a1, b0); mfma16(acc[5][1], a1, b1);
        mfma16(acc[5][2], a1, b2); mfma16(acc[5][3], a1, b3);
        mfma16(acc[6][0], a2, b0); mfma16(acc[6][1], a2, b1);
        mfma16(acc[6][2], a2, b2); mfma16(acc[6][3], a2, b3);
        mfma16(acc[7][0], a3, b0); mfma16(acc[7][1], a3, b1);
        mfma16(acc[7][2], a3, b2); mfma16(acc[7][3], a3, b3);
        __builtin_amdgcn_s_setprio(0);
        __builtin_amdgcn_s_barrier();
    }

    // ---------------- epilogue ----------------
#pragma unroll
    for (int ni = 0; ni < 4; ni++) {
        const int col = n0 + wn + ni * 16 + lr;
        const float bia = bias[col];
        const unsigned h = (unsigned)col / 192u;
        const int rem = col - (int)h * 192;
        const int tq = rem >> 6, d = rem & 63;
#pragma unroll
        for (int mi = 0; mi < 8; mi++) {
            const int row = m0 + wm + mi * 16 + lg * 4;
            if (EPI == 1) {
#pragma unroll
                for (int r = 0; r < 4; r++)
                    Cf[(size_t)(row + r) * N + col] = acc[mi][ni][r] + bia;
            } else {
                const int bb = row >> 10, s = row & 1023;
                const int bh = bb * 16 + (int)h;
                if (tq == 0) {
#pragma unroll
                    for (int r = 0; r < 4; r++)
                        qb[((size_t)bh * 1024 + s + r) * 64 + d] =
                            f2bf((acc[mi][ni][r] + bia) * QSCALE);
                } else if (tq == 1) {
#pragma unroll
                    for (int r = 0; r < 4; r++)
                        kb[((size_t)bh * 1024 + s + r) * 64 + d] = f2bf(acc[mi][ni][r] + bia);
                } else {
                    uint2 pk;
                    pk.x = cvtpk(acc[mi][ni][0] + bia, acc[mi][ni][1] + bia);
                    pk.y = cvtpk(acc[mi][ni][2] + bia, acc[mi][ni][3] + bia);
                    *(uint2*)(vtb + ((size_t)bh * 64 + d) * 1024 + s) = pk;
                }
            }
        }
    }
}

// ---------------- flash attention (swapped QK^T / swapped PV, swizzled LDS) ----------------
__device__ __forceinline__ void softmax_half(f32x4 (&s)[4], float& m, float& l,
                                             f32x4 (&o)[4], unsigned short* pbuf,
                                             int lr, int lg, int x7) {
    float mx = s[0][0];
#pragma unroll
    for (int kt = 0; kt < 4; kt++)
#pragma unroll
        for (int r = 0; r < 4; r++) mx = fmaxf(mx, s[kt][r]);
    mx = fmaxf(mx, __shfl_xor(mx, 16));
    mx = fmaxf(mx, __shfl_xor(mx, 32));
    const float mn = fmaxf(m, mx);
    const float alpha = __builtin_amdgcn_exp2f(m - mn);
    m = mn;
    float p[4][4];
    float rs = 0.f;
#pragma unroll
    for (int kt = 0; kt < 4; kt++)
#pragma unroll
        for (int r = 0; r < 4; r++) {
            p[kt][r] = __builtin_amdgcn_exp2f(s[kt][r] - mn);
            rs += p[kt][r];
        }
    rs += __shfl_xor(rs, 16);
    rs += __shfl_xor(rs, 32);
    l = l * alpha + rs;
#pragma unroll
    for (int mi = 0; mi < 4; mi++)
#pragma unroll
        for (int r = 0; r < 4; r++) o[mi][r] *= alpha;
#pragma unroll
    for (int kt = 0; kt < 4; kt++)
#pragma unroll
        for (int w2 = 0; w2 < 2; w2++) {
            const unsigned pk = cvtpk(p[kt][2 * w2], p[kt][2 * w2 + 1]);
            const int col = (kt * 16 + lg * 4 + 2 * w2) ^ (x7 << 3);
            *(unsigned*)(pbuf + lr * 64 + col) = pk;
        }
}

__global__ __launch_bounds__(256) void attn_fwd(
    const unsigned short* __restrict__ qg, const unsigned short* __restrict__ kg,
    const unsigned short* __restrict__ vtg, unsigned short* __restrict__ vals) {
    __shared__ unsigned short Ks[64 * 64];
    __shared__ unsigned short Vts[64 * 64];
    __shared__ unsigned short Ps[4 * 2048];
    const int tid = threadIdx.x, lane = tid & 63, w = tid >> 6;
    const int lr = lane & 15, lg = lane >> 4;
    const int x7 = lr & 7;
    const int bh = blockIdx.y;
    const int q0 = blockIdx.x * 128 + w * 32;

    const unsigned short* qrowA = qg + ((size_t)bh * 1024 + q0 + lr) * 64;
    const unsigned short* qrowB = qrowA + 16 * 64;
    short8 qA[2], qB[2];
    qA[0] = *(const short8*)(qrowA + lg * 8);
    qA[1] = *(const short8*)(qrowA + 32 + lg * 8);
    qB[0] = *(const short8*)(qrowB + lg * 8);
    qB[1] = *(const short8*)(qrowB + 32 + lg * 8);

    f32x4 oA[4], oB[4];
    float mA = -1e30f, mB = -1e30f, lA = 0.f, lB = 0.f;
#pragma unroll
    for (int i = 0; i < 4; i++) {
        oA[i] = (f32x4){0.f, 0.f, 0.f, 0.f};
        oB[i] = (f32x4){0.f, 0.f, 0.f, 0.f};
    }

    const unsigned short* kb = kg + (size_t)bh * 65536;
    const unsigned short* vb = vtg + (size_t)bh * 65536;
    unsigned short* pwl = Ps + w * 2048;

    const int srow = tid >> 3;
    const int scol = ((tid & 7) ^ (srow & 7)) * 8;

    for (int kv0 = 0; kv0 < 1024; kv0 += 64) {
        __syncthreads();
#pragma unroll
        for (int i = 0; i < 2; i++) {
            gload16(kb + (size_t)(kv0 + i * 32 + srow) * 64 + scol, Ks + i * 2048 + tid * 8);
            gload16(vb + (size_t)(i * 32 + srow) * 1024 + kv0 + scol, Vts + i * 2048 + tid * 8);
        }
        __syncthreads();

        f32x4 sA[4], sB[4];
#pragma unroll
        for (int i = 0; i < 4; i++) {
            sA[i] = (f32x4){0.f, 0.f, 0.f, 0.f};
            sB[i] = (f32x4){0.f, 0.f, 0.f, 0.f};
        }
#pragma unroll
        for (int kt = 0; kt < 4; kt++) {
            const short8 k0 = *(const short8*)(Ks + (kt * 16 + lr) * 64 + ((0 + lg) ^ x7) * 8);
            const short8 k1 = *(const short8*)(Ks + (kt * 16 + lr) * 64 + ((4 + lg) ^ x7) * 8);
            mfma16(sA[kt], k0, qA[0]);
            mfma16(sB[kt], k0, qB[0]);
            mfma16(sA[kt], k1, qA[1]);
            mfma16(sB[kt], k1, qB[1]);
        }

        softmax_half(sA, mA, lA, oA, pwl, lr, lg, x7);
        softmax_half(sB, mB, lB, oB, pwl + 1024, lr, lg, x7);

        short8 pA[2], pB[2];
#pragma unroll
        for (int ks2 = 0; ks2 < 2; ks2++) {
            pA[ks2] = *(const short8*)(pwl + lr * 64 + (((ks2 * 4 + lg) ^ x7) * 8));
            pB[ks2] = *(const short8*)(pwl + 1024 + lr * 64 + (((ks2 * 4 + lg) ^ x7) * 8));
        }
#pragma unroll
        for (int mi = 0; mi < 4; mi++) {
            const short8 v0 = *(const short8*)(Vts + (mi * 16 + lr) * 64 + ((0 + lg) ^ x7) * 8);
            const short8 v1 = *(const short8*)(Vts + (mi * 16 + lr) * 64 + ((4 + lg) ^ x7) * 8);
            mfma16(oA[mi], v0, pA[0]);
            mfma16(oB[mi], v0, pB[0]);
            mfma16(oA[mi], v1, pA[1]);
            mfma16(oB[mi], v1, pB[1]);
        }
    }

    const int bb = bh >> 4, hh = bh & 15;
    {
        const float inv = 1.f / lA;
        unsigned short* vp = vals + (size_t)(bb * 1024 + q0 + lr) * 1024 + hh * 64 + lg * 4;
#pragma unroll
        for (int mi = 0; mi < 4; mi++) {
            uint2 st;
            st.x = cvtpk(oA[mi][0] * inv, oA[mi][1] * inv);
            st.y = cvtpk(oA[mi][2] * inv, oA[mi][3] * inv);
            *(uint2*)(vp + mi * 16) = st;
        }
    }
    {
        const float inv = 1.f / lB;
        unsigned short* vp = vals + (size_t)(bb * 1024 + q0 + 16 + lr) * 1024 + hh * 64 + lg * 4;
#pragma unroll
        for (int mi = 0; mi < 4; mi++) {
            uint2 st;
            st.x = cvtpk(oB[mi][0] * inv, oB[mi][1] * inv);
            st.y = cvtpk(oB[mi][2] * inv, oB[mi][3] * inv);
            *(uint2*)(vp + mi * 16) = st;
        }
    }
}

extern "C" void kernel_launch(void* const* d_in, const int* in_sizes, int n_in,
                              void* d_out, int out_size, void* d_ws, size_t ws_size,
                              hipStream_t stream) {
    const float* x = (const float*)d_in[0];
    const float* w_in = (const float*)d_in[1];
    const float* b_in = (const float*)d_in[2];
    const float* w_out = (const float*)d_in[3];
    const float* b_out = (const float*)d_in[4];
    float* out = (float*)d_out;

    unsigned short* ws = (unsigned short*)d_ws;
    unsigned short* xb = ws;                   // 8388608  (reused as vals)
    unsigned short* winb = xb + 8388608;       // 3145728
    unsigned short* woutb = winb + 3145728;    // 1048576
    unsigned short* qb = woutb + 1048576;      // 8388608
    unsigned short* kb = qb + 8388608;         // 8388608
    unsigned short* vtb = kb + 8388608;        // 8388608
    unsigned short* vals = xb;                 // alias

    auto k0 = gemm256<0>;
    auto k1 = gemm256<1>;
    hipFuncSetAttribute((const void*)k0, hipFuncAttributeMaxDynamicSharedMemorySize, 131072);
    hipFuncSetAttribute((const void*)k1, hipFuncAttributeMaxDynamicSharedMemorySize, 131072);

    cvt_f32_bf16<<<2048, 256, 0, stream>>>(x, xb, 8388608 / 4);
    cvt_f32_bf16<<<1024, 256, 0, stream>>>(w_in, winb, 3145728 / 4);
    cvt_f32_bf16<<<512, 256, 0, stream>>>(w_out, woutb, 1048576 / 4);

    gemm256<0><<<384, 512, 131072, stream>>>(xb, winb, b_in, 1024, 12, 3072,
                                             nullptr, qb, kb, vtb);
    attn_fwd<<<dim3(8, 128), 256, 0, stream>>>(qb, kb, vtb, vals);
    gemm256<1><<<128, 512, 131072, stream>>>(vals, woutb, b_out, 1024, 4, 1024,
                                             out, nullptr, nullptr, nullptr);
}

// Round 5
// 185.790 us; speedup vs baseline: 1.0664x; 1.0664x over previous
//
#include <hip/hip_runtime.h>

typedef short short8 __attribute__((ext_vector_type(8)));
typedef float f32x4 __attribute__((ext_vector_type(4)));

#define AS1 __attribute__((address_space(1)))
#define AS3 __attribute__((address_space(3)))

__device__ __forceinline__ void gload16(const void* g, void* l) {
    __builtin_amdgcn_global_load_lds((const AS1 unsigned int*)g, (AS3 unsigned int*)l, 16, 0, 0);
}

__device__ __forceinline__ unsigned short f2bf(float f) {
    union { float f; unsigned u; } c; c.f = f;
    unsigned r = (c.u + 0x7FFFu + ((c.u >> 16) & 1u)) >> 16;
    return (unsigned short)r;
}

__device__ __forceinline__ unsigned cvtpk(float a, float b) {
    unsigned r;
    asm("v_cvt_pk_bf16_f32 %0, %1, %2" : "=v"(r) : "v"(a), "v"(b));
    return r;
}

__device__ __forceinline__ void mfma16(f32x4& d, short8 a, short8 b) {
    asm("v_mfma_f32_16x16x32_bf16 %0, %1, %2, %0" : "+v"(d) : "v"(a), "v"(b));
}

// q pre-scale: 1/sqrt(64) * log2(e) -> softmax via exp2
#define QSCALE 0.18033688011112042f

// ---------------- fp32 -> bf16 convert ----------------
__global__ __launch_bounds__(256) void cvt_f32_bf16(const float* __restrict__ in,
                                                    unsigned short* __restrict__ out, int n4) {
    int idx = blockIdx.x * 256 + threadIdx.x;
    int stride = gridDim.x * 256;
    for (int i = idx; i < n4; i += stride) {
        float4 v = ((const float4*)in)[i];
        ushort4 o;
        o.x = f2bf(v.x); o.y = f2bf(v.y); o.z = f2bf(v.z); o.w = f2bf(v.w);
        ((ushort4*)out)[i] = o;
    }
}

// ---------------- BMx256 NT GEMM: C = A[M,K]*B[N,K]^T + bias ----------------
// MFR = M-frags per wave (8 -> BM=256, 4 -> BM=128). 512 thr = 8 waves (2M x 4N).
// LDS: As[2][BM][64], Bs[2][256][64] bf16 (128-B rows -> full-line staging).
// Swizzle: phys 16B-chunk = glob ^ (row&7), both-sides (pre-swizzled source).
// Pipeline: issue all tile(t+1) loads at ph0; single vmcnt(0) after ph3 MFMA.
template <int EPI, int MFR>
__global__ __launch_bounds__(512, 2) void gemm256(
    const unsigned short* __restrict__ A, const unsigned short* __restrict__ B,
    const float* __restrict__ bias, int K, int NTN, int N,
    float* __restrict__ Cf, unsigned short* __restrict__ qb,
    unsigned short* __restrict__ kb, unsigned short* __restrict__ vtb) {
    extern __shared__ unsigned short lds[];
    constexpr int ASZ = MFR * 2048;          // elems per A buffer
    unsigned short* As = lds;                // [2][BM][64]
    unsigned short* Bs = lds + 2 * ASZ;      // [2][256][64]

    const int tid = threadIdx.x;
    const int lane = tid & 63;
    const int wid = tid >> 6;
    const int lr = lane & 15, lg = lane >> 4;
    const int x7 = lr & 7;
    const int wm = (wid >> 2) * (MFR * 16);
    const int wn = (wid & 3) * 64;

    const int cpx = gridDim.x >> 3;          // grid % 8 == 0
    const int wg = blockIdx.x;
    const int sw = (wg & 7) * cpx + (wg >> 3);
    const int m0 = (sw / NTN) * (MFR * 32);
    const int n0 = (sw % NTN) * 256;

    // staging: thread covers phys chunk tid&7 of rows j*64 + (tid>>3)
    const int srow8 = tid >> 3;              // 0..63
    const int sgx = ((tid & 7) ^ (srow8 & 7)) * 8;  // pre-swizzled source col (elems)
    const unsigned short* ApJ[4];
    const unsigned short* BpJ[4];
#pragma unroll
    for (int j = 0; j < 4; j++) {
        ApJ[j] = A + (size_t)(m0 + (j < (MFR >> 1) ? j : 0) * 64 + srow8) * K + sgx;
        BpJ[j] = B + (size_t)(n0 + j * 64 + srow8) * K + sgx;
    }

    f32x4 acc[MFR][4];
#pragma unroll
    for (int i = 0; i < MFR; i++)
#pragma unroll
        for (int j = 0; j < 4; j++) acc[i][j] = (f32x4){0.f, 0.f, 0.f, 0.f};

    const int NT = K >> 6;

    // prologue: tile 0 -> buf0
#pragma unroll
    for (int j = 0; j < (MFR >> 1); j++) gload16(ApJ[j], As + j * 4096 + tid * 8);
#pragma unroll
    for (int j = 0; j < 4; j++) gload16(BpJ[j], Bs + j * 4096 + tid * 8);
    asm volatile("s_waitcnt vmcnt(0)" ::: "memory");
    __builtin_amdgcn_s_barrier();

    const int c0 = (lg ^ x7) * 8;
    const int c1 = ((4 + lg) ^ x7) * 8;

    for (int t = 0; t < NT; ++t) {
        const int bufA = (t & 1) * ASZ;
        const int bufB = (t & 1) * 16384;
        const int nbA = bufA ^ ASZ;
        const int nbB = bufB ^ 16384;
        const unsigned short* Ar = As + bufA + (size_t)(wm + lr) * 64;
        const unsigned short* Br = Bs + bufB + (size_t)(wn + lr) * 64;
        short8 af[4], bf[4];

        // ---------- phase 0: ks0, M-half 0 (+ stage tile t+1) ----------
        if (t + 1 < NT) {
            const size_t ko = (size_t)(t + 1) * 64;
#pragma unroll
            for (int j = 0; j < (MFR >> 1); j++)
                gload16(ApJ[j] + ko, As + nbA + j * 4096 + tid * 8);
#pragma unroll
            for (int j = 0; j < 4; j++)
                gload16(BpJ[j] + ko, Bs + nbB + j * 4096 + tid * 8);
        }
#pragma unroll
        for (int ni = 0; ni < 4; ni++) bf[ni] = *(const short8*)(Br + ni * 1024 + c0);
#pragma unroll
        for (int mi = 0; mi < (MFR >> 1); mi++) af[mi] = *(const short8*)(Ar + mi * 1024 + c0);
        __builtin_amdgcn_s_barrier();
        asm volatile("s_waitcnt lgkmcnt(0)" ::: "memory");
        __builtin_amdgcn_sched_barrier(0);
        __builtin_amdgcn_s_setprio(1);
#pragma unroll
        for (int mi = 0; mi < (MFR >> 1); mi++)
#pragma unroll
            for (int ni = 0; ni < 4; ni++) mfma16(acc[mi][ni], af[mi], bf[ni]);
        __builtin_amdgcn_s_setprio(0);
        __builtin_amdgcn_s_barrier();

        // ---------- phase 1: ks0, M-half 1 ----------
#pragma unroll
        for (int mi = 0; mi < (MFR >> 1); mi++)
            af[mi] = *(const short8*)(Ar + ((MFR >> 1) + mi) * 1024 + c0);
        __builtin_amdgcn_s_barrier();
        asm volatile("s_waitcnt lgkmcnt(0)" ::: "memory");
        __builtin_amdgcn_sched_barrier(0);
        __builtin_amdgcn_s_setprio(1);
#pragma unroll
        for (int mi = 0; mi < (MFR >> 1); mi++)
#pragma unroll
            for (int ni = 0; ni < 4; ni++) mfma16(acc[(MFR >> 1) + mi][ni], af[mi], bf[ni]);
        __builtin_amdgcn_s_setprio(0);
        __builtin_amdgcn_s_barrier();

        // ---------- phase 2: ks1, M-half 0 ----------
#pragma unroll
        for (int ni = 0; ni < 4; ni++) bf[ni] = *(const short8*)(Br + ni * 1024 + c1);
#pragma unroll
        for (int mi = 0; mi < (MFR >> 1); mi++) af[mi] = *(const short8*)(Ar + mi * 1024 + c1);
        __builtin_amdgcn_s_barrier();
        asm volatile("s_waitcnt lgkmcnt(0)" ::: "memory");
        __builtin_amdgcn_sched_barrier(0);
        __builtin_amdgcn_s_setprio(1);
#pragma unroll
        for (int mi = 0; mi < (MFR >> 1); mi++)
#pragma unroll
            for (int ni = 0; ni < 4; ni++) mfma16(acc[mi][ni], af[mi], bf[ni]);
        __builtin_amdgcn_s_setprio(0);
        __builtin_amdgcn_s_barrier();

        // ---------- phase 3: ks1, M-half 1 (+ vmcnt(0) for tile t+1) ----------
#pragma unroll
        for (int mi = 0; mi < (MFR >> 1); mi++)
            af[mi] = *(const short8*)(Ar + ((MFR >> 1) + mi) * 1024 + c1);
        __builtin_amdgcn_s_barrier();
        asm volatile("s_waitcnt lgkmcnt(0)" ::: "memory");
        __builtin_amdgcn_sched_barrier(0);
        __builtin_amdgcn_s_setprio(1);
#pragma unroll
        for (int mi = 0; mi < (MFR >> 1); mi++)
#pragma unroll
            for (int ni = 0; ni < 4; ni++) mfma16(acc[(MFR >> 1) + mi][ni], af[mi], bf[ni]);
        __builtin_amdgcn_s_setprio(0);
        asm volatile("s_waitcnt vmcnt(0)" ::: "memory");
        __builtin_amdgcn_s_barrier();
    }

    // ---------------- epilogue ----------------
#pragma unroll
    for (int ni = 0; ni < 4; ni++) {
        const int col = n0 + wn + ni * 16 + lr;
        const float bia = bias[col];
        const unsigned h = (unsigned)col / 192u;
        const int rem = col - (int)h * 192;
        const int tq = rem >> 6, d = rem & 63;
#pragma unroll
        for (int mi = 0; mi < MFR; mi++) {
            const int row = m0 + wm + mi * 16 + lg * 4;
            if (EPI == 1) {
#pragma unroll
                for (int r = 0; r < 4; r++)
                    Cf[(size_t)(row + r) * N + col] = acc[mi][ni][r] + bia;
            } else {
                const int bb = row >> 10, s = row & 1023;
                const int bh = bb * 16 + (int)h;
                if (tq == 0) {
#pragma unroll
                    for (int r = 0; r < 4; r++)
                        qb[((size_t)bh * 1024 + s + r) * 64 + d] =
                            f2bf((acc[mi][ni][r] + bia) * QSCALE);
                } else if (tq == 1) {
#pragma unroll
                    for (int r = 0; r < 4; r++)
                        kb[((size_t)bh * 1024 + s + r) * 64 + d] = f2bf(acc[mi][ni][r] + bia);
                } else {
                    uint2 pk;
                    pk.x = cvtpk(acc[mi][ni][0] + bia, acc[mi][ni][1] + bia);
                    pk.y = cvtpk(acc[mi][ni][2] + bia, acc[mi][ni][3] + bia);
                    *(uint2*)(vtb + ((size_t)bh * 64 + d) * 1024 + s) = pk;
                }
            }
        }
    }
}

// ---------------- flash attention (round-3 proven version) ----------------
__device__ __forceinline__ void softmax_half(f32x4 (&s)[4], float& m, float& l,
                                             f32x4 (&o)[4], unsigned short* pbuf,
                                             int lr, int lg, int x7) {
    float mx = s[0][0];
#pragma unroll
    for (int kt = 0; kt < 4; kt++)
#pragma unroll
        for (int r = 0; r < 4; r++) mx = fmaxf(mx, s[kt][r]);
    mx = fmaxf(mx, __shfl_xor(mx, 16));
    mx = fmaxf(mx, __shfl_xor(mx, 32));
    const float mn = fmaxf(m, mx);
    const float alpha = __builtin_amdgcn_exp2f(m - mn);
    m = mn;
    float p[4][4];
    float rs = 0.f;
#pragma unroll
    for (int kt = 0; kt < 4; kt++)
#pragma unroll
        for (int r = 0; r < 4; r++) {
            p[kt][r] = __builtin_amdgcn_exp2f(s[kt][r] - mn);
            rs += p[kt][r];
        }
    rs += __shfl_xor(rs, 16);
    rs += __shfl_xor(rs, 32);
    l = l * alpha + rs;
#pragma unroll
    for (int mi = 0; mi < 4; mi++)
#pragma unroll
        for (int r = 0; r < 4; r++) o[mi][r] *= alpha;
#pragma unroll
    for (int kt = 0; kt < 4; kt++)
#pragma unroll
        for (int w2 = 0; w2 < 2; w2++) {
            const unsigned pk = cvtpk(p[kt][2 * w2], p[kt][2 * w2 + 1]);
            const int col = (kt * 16 + lg * 4 + 2 * w2) ^ (x7 << 3);
            *(unsigned*)(pbuf + lr * 64 + col) = pk;
        }
}

__global__ __launch_bounds__(256) void attn_fwd(
    const unsigned short* __restrict__ qg, const unsigned short* __restrict__ kg,
    const unsigned short* __restrict__ vtg, unsigned short* __restrict__ vals) {
    __shared__ unsigned short Ks[64 * 64];
    __shared__ unsigned short Vts[64 * 64];
    __shared__ unsigned short Ps[4 * 2048];
    const int tid = threadIdx.x, lane = tid & 63, w = tid >> 6;
    const int lr = lane & 15, lg = lane >> 4;
    const int x7 = lr & 7;
    const int bh = blockIdx.y;
    const int q0 = blockIdx.x * 128 + w * 32;

    const unsigned short* qrowA = qg + ((size_t)bh * 1024 + q0 + lr) * 64;
    const unsigned short* qrowB = qrowA + 16 * 64;
    short8 qA[2], qB[2];
    qA[0] = *(const short8*)(qrowA + lg * 8);
    qA[1] = *(const short8*)(qrowA + 32 + lg * 8);
    qB[0] = *(const short8*)(qrowB + lg * 8);
    qB[1] = *(const short8*)(qrowB + 32 + lg * 8);

    f32x4 oA[4], oB[4];
    float mA = -1e30f, mB = -1e30f, lA = 0.f, lB = 0.f;
#pragma unroll
    for (int i = 0; i < 4; i++) {
        oA[i] = (f32x4){0.f, 0.f, 0.f, 0.f};
        oB[i] = (f32x4){0.f, 0.f, 0.f, 0.f};
    }

    const unsigned short* kb = kg + (size_t)bh * 65536;
    const unsigned short* vb = vtg + (size_t)bh * 65536;
    unsigned short* pwl = Ps + w * 2048;

    const int srow = tid >> 3;
    const int scol = ((tid & 7) ^ (srow & 7)) * 8;

    for (int kv0 = 0; kv0 < 1024; kv0 += 64) {
        __syncthreads();
#pragma unroll
        for (int i = 0; i < 2; i++) {
            gload16(kb + (size_t)(kv0 + i * 32 + srow) * 64 + scol, Ks + i * 2048 + tid * 8);
            gload16(vb + (size_t)(i * 32 + srow) * 1024 + kv0 + scol, Vts + i * 2048 + tid * 8);
        }
        __syncthreads();

        f32x4 sA[4], sB[4];
#pragma unroll
        for (int i = 0; i < 4; i++) {
            sA[i] = (f32x4){0.f, 0.f, 0.f, 0.f};
            sB[i] = (f32x4){0.f, 0.f, 0.f, 0.f};
        }
#pragma unroll
        for (int kt = 0; kt < 4; kt++) {
            const short8 k0 = *(const short8*)(Ks + (kt * 16 + lr) * 64 + ((0 + lg) ^ x7) * 8);
            const short8 k1 = *(const short8*)(Ks + (kt * 16 + lr) * 64 + ((4 + lg) ^ x7) * 8);
            mfma16(sA[kt], k0, qA[0]);
            mfma16(sB[kt], k0, qB[0]);
            mfma16(sA[kt], k1, qA[1]);
            mfma16(sB[kt], k1, qB[1]);
        }

        softmax_half(sA, mA, lA, oA, pwl, lr, lg, x7);
        softmax_half(sB, mB, lB, oB, pwl + 1024, lr, lg, x7);

        short8 pA[2], pB[2];
#pragma unroll
        for (int ks2 = 0; ks2 < 2; ks2++) {
            pA[ks2] = *(const short8*)(pwl + lr * 64 + (((ks2 * 4 + lg) ^ x7) * 8));
            pB[ks2] = *(const short8*)(pwl + 1024 + lr * 64 + (((ks2 * 4 + lg) ^ x7) * 8));
        }
#pragma unroll
        for (int mi = 0; mi < 4; mi++) {
            const short8 v0 = *(const short8*)(Vts + (mi * 16 + lr) * 64 + ((0 + lg) ^ x7) * 8);
            const short8 v1 = *(const short8*)(Vts + (mi * 16 + lr) * 64 + ((4 + lg) ^ x7) * 8);
            mfma16(oA[mi], v0, pA[0]);
            mfma16(oB[mi], v0, pB[0]);
            mfma16(oA[mi], v1, pA[1]);
            mfma16(oB[mi], v1, pB[1]);
        }
    }

    const int bb = bh >> 4, hh = bh & 15;
    {
        const float inv = 1.f / lA;
        unsigned short* vp = vals + (size_t)(bb * 1024 + q0 + lr) * 1024 + hh * 64 + lg * 4;
#pragma unroll
        for (int mi = 0; mi < 4; mi++) {
            uint2 st;
            st.x = cvtpk(oA[mi][0] * inv, oA[mi][1] * inv);
            st.y = cvtpk(oA[mi][2] * inv, oA[mi][3] * inv);
            *(uint2*)(vp + mi * 16) = st;
        }
    }
    {
        const float inv = 1.f / lB;
        unsigned short* vp = vals + (size_t)(bb * 1024 + q0 + 16 + lr) * 1024 + hh * 64 + lg * 4;
#pragma unroll
        for (int mi = 0; mi < 4; mi++) {
            uint2 st;
            st.x = cvtpk(oB[mi][0] * inv, oB[mi][1] * inv);
            st.y = cvtpk(oB[mi][2] * inv, oB[mi][3] * inv);
            *(uint2*)(vp + mi * 16) = st;
        }
    }
}

extern "C" void kernel_launch(void* const* d_in, const int* in_sizes, int n_in,
                              void* d_out, int out_size, void* d_ws, size_t ws_size,
                              hipStream_t stream) {
    const float* x = (const float*)d_in[0];
    const float* w_in = (const float*)d_in[1];
    const float* b_in = (const float*)d_in[2];
    const float* w_out = (const float*)d_in[3];
    const float* b_out = (const float*)d_in[4];
    float* out = (float*)d_out;

    unsigned short* ws = (unsigned short*)d_ws;
    unsigned short* xb = ws;                   // 8388608  (reused as vals)
    unsigned short* winb = xb + 8388608;       // 3145728
    unsigned short* woutb = winb + 3145728;    // 1048576
    unsigned short* qb = woutb + 1048576;      // 8388608  (Q [bh,1024,64], pre-scaled)
    unsigned short* kb = qb + 8388608;         // 8388608
    unsigned short* vtb = kb + 8388608;        // 8388608  (V^T [bh,64,1024])
    unsigned short* vals = xb;                 // alias

    hipFuncSetAttribute((const void*)gemm256<0, 8>,
                        hipFuncAttributeMaxDynamicSharedMemorySize, 131072);
    hipFuncSetAttribute((const void*)gemm256<1, 4>,
                        hipFuncAttributeMaxDynamicSharedMemorySize, 98304);

    cvt_f32_bf16<<<2048, 256, 0, stream>>>(x, xb, 8388608 / 4);
    cvt_f32_bf16<<<1024, 256, 0, stream>>>(w_in, winb, 3145728 / 4);
    cvt_f32_bf16<<<512, 256, 0, stream>>>(w_out, woutb, 1048576 / 4);

    // QKV: BM=256 -> grid 32x12 = 384; proj: BM=128 -> grid 64x4 = 256
    gemm256<0, 8><<<384, 512, 131072, stream>>>(xb, winb, b_in, 1024, 12, 3072,
                                                nullptr, qb, kb, vtb);
    attn_fwd<<<dim3(8, 128), 256, 0, stream>>>(qb, kb, vtb, vals);
    gemm256<1, 4><<<256, 512, 98304, stream>>>(vals, woutb, b_out, 1024, 4, 1024,
                                               out, nullptr, nullptr, nullptr);
}